// Round 1
// baseline (1501.201 us; speedup 1.0000x reference)
//
#include <hip/hip_runtime.h>

#define HIDDEN 4096
#define EPS 1e-6f

// One block per token row. 256 threads; each thread owns 4 float4 (16 floats)
// of the 4096-element row. Single pass: sum tp partials in registers, reduce
// sum-of-squares across the block, scale, store. HBM-bound: 1.074 GB read +
// 0.268 GB write -> ~213 us floor at 6.3 TB/s.
template <int TP>
__global__ __launch_bounds__(256) void ar_rmsnorm_kernel(
    const float* __restrict__ hs,      // [TP, tokens, HIDDEN]
    const float* __restrict__ weight,  // [HIDDEN]
    float* __restrict__ out,           // [tokens, HIDDEN]
    int tokens) {
    const int row = blockIdx.x;
    const int tid = threadIdx.x;

    const size_t row_f4 = (size_t)row * (HIDDEN / 4);   // row offset in float4 units
    const size_t slice_f4 = (size_t)tokens * (HIDDEN / 4);  // tp-slice stride in float4

    const float4* __restrict__ hs4 = (const float4*)hs;

    float4 acc[4];
    float ss = 0.0f;

#pragma unroll
    for (int k = 0; k < 4; ++k) {
        const size_t p = row_f4 + (size_t)tid + (size_t)k * 256;
        float4 r = hs4[p];
#pragma unroll
        for (int t = 1; t < TP; ++t) {
            float4 v = hs4[(size_t)t * slice_f4 + p];
            r.x += v.x; r.y += v.y; r.z += v.z; r.w += v.w;
        }
        acc[k] = r;
        ss += r.x * r.x + r.y * r.y + r.z * r.z + r.w * r.w;
    }

    // Wave-64 reduction
#pragma unroll
    for (int off = 32; off > 0; off >>= 1)
        ss += __shfl_down(ss, off, 64);

    __shared__ float smem[4];
    const int wave = tid >> 6;
    if ((tid & 63) == 0) smem[wave] = ss;
    __syncthreads();
    const float tot = smem[0] + smem[1] + smem[2] + smem[3];

    const float rs = rsqrtf(tot * (1.0f / (float)HIDDEN) + EPS);

    const float4* __restrict__ w4 = (const float4*)weight;
    float4* __restrict__ o4 = (float4*)out;

#pragma unroll
    for (int k = 0; k < 4; ++k) {
        const int wp = tid + k * 256;
        float4 w = w4[wp];
        float4 r = acc[k];
        float4 o;
        o.x = r.x * rs * w.x;
        o.y = r.y * rs * w.y;
        o.z = r.z * rs * w.z;
        o.w = r.w * rs * w.w;
        o4[row_f4 + (size_t)wp] = o;
    }
}

// Dynamic-TP fallback (not expected to be used; reference has tp=4).
__global__ __launch_bounds__(256) void ar_rmsnorm_kernel_dyn(
    const float* __restrict__ hs, const float* __restrict__ weight,
    float* __restrict__ out, int tokens, int tp) {
    const int row = blockIdx.x;
    const int tid = threadIdx.x;
    const size_t row_f4 = (size_t)row * (HIDDEN / 4);
    const size_t slice_f4 = (size_t)tokens * (HIDDEN / 4);
    const float4* __restrict__ hs4 = (const float4*)hs;

    float4 acc[4];
    float ss = 0.0f;
#pragma unroll
    for (int k = 0; k < 4; ++k) {
        const size_t p = row_f4 + (size_t)tid + (size_t)k * 256;
        float4 r = make_float4(0.f, 0.f, 0.f, 0.f);
        for (int t = 0; t < tp; ++t) {
            float4 v = hs4[(size_t)t * slice_f4 + p];
            r.x += v.x; r.y += v.y; r.z += v.z; r.w += v.w;
        }
        acc[k] = r;
        ss += r.x * r.x + r.y * r.y + r.z * r.z + r.w * r.w;
    }
#pragma unroll
    for (int off = 32; off > 0; off >>= 1)
        ss += __shfl_down(ss, off, 64);
    __shared__ float smem[4];
    const int wave = tid >> 6;
    if ((tid & 63) == 0) smem[wave] = ss;
    __syncthreads();
    const float tot = smem[0] + smem[1] + smem[2] + smem[3];
    const float rs = rsqrtf(tot * (1.0f / (float)HIDDEN) + EPS);

    const float4* __restrict__ w4 = (const float4*)weight;
    float4* __restrict__ o4 = (float4*)out;
#pragma unroll
    for (int k = 0; k < 4; ++k) {
        const int wp = tid + k * 256;
        float4 w = w4[wp];
        float4 r = acc[k];
        float4 o;
        o.x = r.x * rs * w.x;
        o.y = r.y * rs * w.y;
        o.z = r.z * rs * w.z;
        o.w = r.w * rs * w.w;
        o4[row_f4 + (size_t)wp] = o;
    }
}

extern "C" void kernel_launch(void* const* d_in, const int* in_sizes, int n_in,
                              void* d_out, int out_size, void* d_ws, size_t ws_size,
                              hipStream_t stream) {
    // Inputs (setup_inputs order): hidden_states [tp,tokens,HIDDEN] fp32,
    // residual [tokens,HIDDEN] fp32 (UNUSED by reference), weight [HIDDEN] fp32.
    const float* hs = (const float*)d_in[0];
    const float* weight = (const float*)d_in[2];
    float* out = (float*)d_out;

    const int tokens = out_size / HIDDEN;              // 16384
    const int tp = in_sizes[0] / out_size;             // 4

    dim3 grid(tokens), block(256);
    if (tp == 4) {
        ar_rmsnorm_kernel<4><<<grid, block, 0, stream>>>(hs, weight, out, tokens);
    } else {
        ar_rmsnorm_kernel_dyn<<<grid, block, 0, stream>>>(hs, weight, out, tokens, tp);
    }
}